// Round 13
// baseline (335.088 us; speedup 1.0000x reference)
//
#include <hip/hip_runtime.h>
#include <hip/hip_bf16.h>
#include <hip/hip_cooperative_groups.h>

namespace cg = cooperative_groups;

#define DIM 32
#define RCR 512             // receivers per coarse region (r_local = 9 bits)
#define NCMAX 256           // max regions (N <= 131072)
#define CAPC 9216           // region capacity (ints); mean 8192, +11 sigma
#define GRID 256            // cooperative grid: 1 block/CU
#define BLK 1024            // 16 waves/block -> 4 waves/SIMD co-resident

// ---------------- f16 / bf16 <-> fp32 helpers ------------------------------
__device__ __forceinline__ float b2f(ushort h) {
    union { float f; unsigned u; } u; u.u = ((unsigned)h) << 16; return u.f;
}
__device__ __forceinline__ float h2f(ushort u) {
    _Float16 h; __builtin_memcpy(&h, &u, 2); return (float)h;
}
__device__ __forceinline__ ushort f2h(float f) {
    _Float16 h = (_Float16)f; ushort u; __builtin_memcpy(&u, &h, 2); return u;
}
__device__ __forceinline__ int load_idx(const int* __restrict__ idx, size_t pos,
                                        int mode, int n) {
    int v = mode ? idx[2 * pos] : idx[pos];
    return v < 0 ? 0 : (v >= n ? n - 1 : v);
}
__device__ __forceinline__ float load_f(const void* p, size_t i, int bf) {
    return bf ? b2f(((const ushort*)p)[i]) : ((const float*)p)[i];
}

// ---------------------------------------------------------------------------
// Phase-shared LDS (max member ~38.1 KB)
// ---------------------------------------------------------------------------
union SMem {
    struct { float sW[3][DIM * DIM]; float sx[32][DIM]; } qkv;        // 16.4 KB
    struct { int h[NCMAX]; int goff[NCMAX]; } place;                  //  2 KB
    struct { unsigned eL[CAPC]; int cnt[RCR]; int wsum[16]; } sort;   // 39 KB
    struct { float sWo[DIM * DIM]; unsigned sQ[128 * 16];
             float accS[128][DIM + 1]; float Zs[128]; } agg;          // 29.7 KB
};

// ---------------------------------------------------------------------------
// Mega-kernel: qkv -> place -> rsort -> agg with grid-wide syncs.
// Algorithms identical to round 12's 4 kernels, re-mapped onto 256x1024.
// ---------------------------------------------------------------------------
__global__ void __launch_bounds__(BLK)
mega_kernel(const void* __restrict__ x_, const int* __restrict__ idx,
            const void* __restrict__ Wq_, const void* __restrict__ Wk_,
            const void* __restrict__ Wv_, const void* __restrict__ Wo_,
            int N, int E, int nc,
            ushort* __restrict__ Q, ushort* __restrict__ KV,
            unsigned* __restrict__ bedges, unsigned* __restrict__ gcur,
            int* __restrict__ rbase, int* __restrict__ rcount,
            float* __restrict__ out) {
    cg::grid_group grid = cg::this_grid();
    __shared__ SMem sm;
    __shared__ int sBf, sMode;

    const int tid = threadIdx.x;

    // ---- phase 0: probes + gcur init ----
    if (tid < 64) {
        int e = (((const ushort*)x_)[2 * tid] >> 7) & 0xFF;
        unsigned long long bb = __ballot(e >= 100 && e <= 135);
        unsigned long long mm = __ballot(idx[2 * tid + 1] != 0);
        if (tid == 0) { sBf = (__popcll(bb) >= 56); sMode = (mm == 0ULL); }
    }
    if (blockIdx.x == 0) {
        for (int i = tid; i < nc; i += BLK) gcur[i] = (unsigned)i * CAPC;
    }
    __syncthreads();
    const int bf = sBf, mode = sMode;

    // ---- phase 1: QKV GEMM (f16, Q pre-scaled, KV interleaved 128 B) ----
    for (int i = tid; i < DIM * DIM; i += BLK) {
        sm.qkv.sW[0][i] = load_f(Wq_, i, bf);
        sm.qkv.sW[1][i] = load_f(Wk_, i, bf);
        sm.qkv.sW[2][i] = load_f(Wv_, i, bf);
    }
    {
        const int lr = tid >> 5;          // 0..31
        const int d  = tid & 31;
        for (int base = blockIdx.x * 32; base < N; base += GRID * 32) {
            const int row = base + lr;
            __syncthreads();              // protect sx from prev-iter readers
            if (row < N) sm.qkv.sx[lr][d] = load_f(x_, (size_t)row * DIM + d, bf);
            __syncthreads();
            if (row < N) {
                float aq = 0.f, ak = 0.f, av = 0.f;
#pragma unroll
                for (int k = 0; k < DIM; ++k) {
                    const float xk = sm.qkv.sx[lr][k];
                    aq += xk * sm.qkv.sW[0][k * DIM + d];
                    ak += xk * sm.qkv.sW[1][k * DIM + d];
                    av += xk * sm.qkv.sW[2][k * DIM + d];
                }
                Q[(size_t)row * DIM + d]      = f2h(aq * 0.17677669529663687f);
                KV[(size_t)row * 64 + d]      = f2h(ak);
                KV[(size_t)row * 64 + 32 + d] = f2h(av);
            }
        }
    }
    grid.sync();

    // ---- phase 2: place (two-pass hist + reserve + scatter) ----
    {
        const int per = (E + GRID - 1) / GRID;
        const int e0 = blockIdx.x * per;
        const int e1 = min(e0 + per, E);
        for (int i = tid; i < nc; i += BLK) sm.place.h[i] = 0;
        __syncthreads();
        for (int e = e0 + tid; e < e1; e += BLK) {
            const int r = load_idx(idx, (size_t)E + e, mode, N);
            atomicAdd(&sm.place.h[r >> 9], 1);
        }
        __syncthreads();
        for (int i = tid; i < nc; i += BLK) {
            const int v = sm.place.h[i];
            sm.place.goff[i] = v ? (int)atomicAdd(&gcur[i], (unsigned)v) : 0;
            sm.place.h[i] = 0;           // reuse as local cursor
        }
        __syncthreads();
        for (int e = e0 + tid; e < e1; e += BLK) {
            const int r = load_idx(idx, (size_t)E + e, mode, N);
            const int s = load_idx(idx, (size_t)e, mode, N);
            const int cb = r >> 9;
            const int p = sm.place.goff[cb] + atomicAdd(&sm.place.h[cb], 1);
            if (p < (cb + 1) * CAPC)     // overflow guard (11-sigma headroom)
                bedges[p] = (unsigned)s | ((unsigned)(r & (RCR - 1)) << 17);
        }
    }
    grid.sync();

    // ---- phase 3: rsort (LDS counting sort per region -> CSR) ----
    for (int c = blockIdx.x; c < nc; c += GRID) {
        const unsigned s0 = (unsigned)c * CAPC;
        int m = (int)(gcur[c] - s0);
        if (m < 0) m = 0; if (m > CAPC) m = CAPC;

        if (tid < RCR) sm.sort.cnt[tid] = 0;
        __syncthreads();
        for (int i = tid; i < m; i += BLK) {
            const unsigned e = bedges[s0 + i];
            sm.sort.eL[i] = e;
            atomicAdd(&sm.sort.cnt[(e >> 17) & (RCR - 1)], 1);
        }
        __syncthreads();

        const int lane = tid & 63, w = tid >> 6;
        const int v = (tid < RCR) ? sm.sort.cnt[tid] : 0;
        int x = v;
#pragma unroll
        for (int o = 1; o < 64; o <<= 1) {
            int t = __shfl_up(x, o); if (lane >= o) x += t;
        }
        if (tid < RCR && lane == 63) sm.sort.wsum[w] = x;
        __syncthreads();
        if (tid == 0) {
            int a = 0;
#pragma unroll
            for (int k = 0; k < 8; ++k) { int t = sm.sort.wsum[k]; sm.sort.wsum[k] = a; a += t; }
        }
        __syncthreads();
        int excl = 0;
        if (tid < RCR) {
            excl = x - v + sm.sort.wsum[w];
            rbase[c * RCR + tid]  = (int)s0 + excl;
            rcount[c * RCR + tid] = v;
        }
        __syncthreads();
        if (tid < RCR) sm.sort.cnt[tid] = (int)s0 + excl;
        __syncthreads();
        for (int i = tid; i < m; i += BLK) {
            const unsigned e = sm.sort.eL[i];
            const int p = atomicAdd(&sm.sort.cnt[(e >> 17) & (RCR - 1)], 1);
            bedges[p] = e & 0x1FFFF;
        }
        __syncthreads();
    }
    grid.sync();

    // ---- phase 4: agg (wave-per-receiver, x2-pipelined; fused epilogue) ----
    for (int i = tid; i < DIM * DIM; i += BLK) sm.agg.sWo[i] = load_f(Wo_, i, bf);
    {
        const int ngrp = (N + 127) >> 7;      // 128 receivers per group
        const int w    = tid >> 6;            // 0..15
        const int lane = tid & 63;
        const int i8   = lane >> 3;           // edge sub-slot 0..7
        const int j    = lane & 7;            // channel group 0..7
        const int lr   = tid >> 5;            // epilogue row 0..31
        const int d    = tid & 31;

        for (int g = blockIdx.x; g < ngrp; g += GRID) {
            const int r0 = g << 7;
            const int nr = min(128, N - r0);
            __syncthreads();                  // protect sQ/accS from prev iter
            for (int i = tid; i < nr * 16; i += BLK)
                sm.agg.sQ[i] = ((const unsigned*)(Q + (size_t)r0 * DIM))[i];
            __syncthreads();

            for (int rl = w; rl < nr; rl += 16) {
                const int r   = r0 + rl;
                const int deg = rcount[r];
                const int o0  = rbase[r];
                const ushort4 qh = *(const ushort4*)((const ushort*)sm.agg.sQ + rl * DIM + j * 4);
                const float q0 = h2f(qh.x), q1 = h2f(qh.y), q2 = h2f(qh.z), q3 = h2f(qh.w);

                float ax = 0.f, ay = 0.f, az = 0.f, aw = 0.f, zs = 0.f;
                const int chunks = (deg + 7) >> 3;
                const int dm1 = deg - 1;

                int cc = 0;
                for (; cc + 2 <= chunks; cc += 2) {
                    const int c0 = cc * 8 + i8;
                    const int c1 = c0 + 8;
                    const bool ok0 = (c0 < deg);
                    const bool ok1 = (c1 < deg);
                    const int sA = (int)bedges[o0 + (ok0 ? c0 : dm1)];
                    const int sB = (int)bedges[o0 + (ok1 ? c1 : dm1)];
                    const ushort* kvA = KV + (size_t)sA * 64;
                    const ushort* kvB = KV + (size_t)sB * 64;

                    const ushort4 khA = *(const ushort4*)(kvA + j * 4);
                    const ushort4 vhA = *(const ushort4*)(kvA + 32 + j * 4);
                    const ushort4 khB = *(const ushort4*)(kvB + j * 4);
                    const ushort4 vhB = *(const ushort4*)(kvB + 32 + j * 4);

                    float pA = h2f(khA.x) * q0;
                    float pB = h2f(khB.x) * q0;
                    pA = fmaf(h2f(khA.y), q1, pA);  pB = fmaf(h2f(khB.y), q1, pB);
                    pA = fmaf(h2f(khA.z), q2, pA);  pB = fmaf(h2f(khB.z), q2, pB);
                    pA = fmaf(h2f(khA.w), q3, pA);  pB = fmaf(h2f(khB.w), q3, pB);

                    pA += __shfl_xor(pA, 1);        pB += __shfl_xor(pB, 1);
                    pA += __shfl_xor(pA, 2);        pB += __shfl_xor(pB, 2);
                    pA += __shfl_xor(pA, 4);        pB += __shfl_xor(pB, 4);

                    pA = fminf(fmaxf(pA, -60.f), 60.f);
                    pB = fminf(fmaxf(pB, -60.f), 60.f);
                    const float aA = ok0 ? __expf(pA) : 0.f;
                    const float aB = ok1 ? __expf(pB) : 0.f;

                    ax = fmaf(h2f(vhA.x), aA, ax);  ax = fmaf(h2f(vhB.x), aB, ax);
                    ay = fmaf(h2f(vhA.y), aA, ay);  ay = fmaf(h2f(vhB.y), aB, ay);
                    az = fmaf(h2f(vhA.z), aA, az);  az = fmaf(h2f(vhB.z), aB, az);
                    aw = fmaf(h2f(vhA.w), aA, aw);  aw = fmaf(h2f(vhB.w), aB, aw);
                    zs += aA + aB;
                }
                if (cc < chunks) {               // odd remainder chunk
                    const int c = cc * 8 + i8;
                    const bool ok = (c < deg);
                    const int s = (int)bedges[o0 + (ok ? c : dm1)];
                    const ushort* kv = KV + (size_t)s * 64;
                    const ushort4 kh = *(const ushort4*)(kv + j * 4);
                    const ushort4 vh = *(const ushort4*)(kv + 32 + j * 4);

                    float p = h2f(kh.x) * q0;
                    p = fmaf(h2f(kh.y), q1, p);
                    p = fmaf(h2f(kh.z), q2, p);
                    p = fmaf(h2f(kh.w), q3, p);
                    p += __shfl_xor(p, 1);
                    p += __shfl_xor(p, 2);
                    p += __shfl_xor(p, 4);
                    p = fminf(fmaxf(p, -60.f), 60.f);
                    const float a = ok ? __expf(p) : 0.f;

                    ax = fmaf(h2f(vh.x), a, ax);
                    ay = fmaf(h2f(vh.y), a, ay);
                    az = fmaf(h2f(vh.z), a, az);
                    aw = fmaf(h2f(vh.w), a, aw);
                    zs += a;
                }
#pragma unroll
                for (int o = 8; o < 64; o <<= 1) {
                    ax += __shfl_xor(ax, o); ay += __shfl_xor(ay, o);
                    az += __shfl_xor(az, o); aw += __shfl_xor(aw, o);
                    zs += __shfl_xor(zs, o);
                }
                if (i8 == 0) {
                    float* ar = sm.agg.accS[rl];
                    ar[j * 4 + 0] = ax; ar[j * 4 + 1] = ay;
                    ar[j * 4 + 2] = az; ar[j * 4 + 3] = aw;
                    if (j == 0) sm.agg.Zs[rl] = zs;
                }
            }
            __syncthreads();

            // epilogue: 1024 threads = 32 rows x 32 cols; 4 passes = 128 rows
#pragma unroll
            for (int it = 0; it < 4; ++it) {
                const int rl = it * 32 + lr;
                if (rl < nr) {
                    const float inv = 1.f / (sm.agg.Zs[rl] + 1e-6f);
                    float o = 0.f;
#pragma unroll
                    for (int k = 0; k < DIM; ++k)
                        o += sm.agg.accS[rl][k] * sm.agg.sWo[k * DIM + d];
                    const size_t oi = (size_t)(r0 + rl) * DIM + d;
                    out[oi] = load_f(x_, oi, bf) + inv * o;
                }
            }
        }
    }
}

// ---------------------------------------------------------------------------
extern "C" void kernel_launch(void* const* d_in, const int* in_sizes, int n_in,
                              void* d_out, int out_size, void* d_ws, size_t ws_size,
                              hipStream_t stream) {
    const void* x   = d_in[0];
    const int*  idx = (const int*)d_in[1];
    const void* Wq  = d_in[2];
    const void* Wk  = d_in[3];
    const void* Wv  = d_in[4];
    const void* Wo  = d_in[5];
    float* out = (float*)d_out;           // fp32 reference output

    int N = in_sizes[0] / DIM;            // 100000
    int E = in_sizes[1] / 2;              // 1600000
    int nc = (N + RCR - 1) / RCR;         // 196 coarse regions
    const size_t N32 = (size_t)N * DIM;

    // Workspace (~28 MB): Q f16 | KV f16 | bedges | gcur | rbase | rcount
    ushort*   Q      = (ushort*)d_ws;
    ushort*   KV     = Q + N32;                          // N * 64 halves
    unsigned* bedges = (unsigned*)(KV + (size_t)N * 64); // nc * CAPC
    unsigned* gcur   = bedges + (size_t)nc * CAPC;
    int*      rbase  = (int*)(gcur + NCMAX);
    int*      rcount = rbase + (size_t)nc * RCR;

    void* args[] = { (void*)&x, (void*)&idx, (void*)&Wq, (void*)&Wk,
                     (void*)&Wv, (void*)&Wo, (void*)&N, (void*)&E, (void*)&nc,
                     (void*)&Q, (void*)&KV, (void*)&bedges, (void*)&gcur,
                     (void*)&rbase, (void*)&rcount, (void*)&out };
    hipLaunchCooperativeKernel((const void*)mega_kernel, dim3(GRID), dim3(BLK),
                               args, 0, stream);
}

// Round 15
// 310.698 us; speedup vs baseline: 1.0785x; 1.0785x over previous
//
#include <hip/hip_runtime.h>
#include <hip/hip_bf16.h>

#define DIM 32
#define RCR 512             // receivers per region (r_local = 9 bits)
#define NCMAX 256           // max regions (N <= 131072)
#define PBLK 64             // place blocks
#define SUBCAP 200          // ints per (region, place-block) cell; mean 128, +6.4 sigma
#define REGSZ (PBLK * SUBCAP)   // 12800 ints per region
#define QCAP 2432           // quarter edge cap; mean 2048, +8.5 sigma
#define SENT 0xFFFFFFFFu

// ---------------- f16 / bf16 <-> fp32 helpers ------------------------------
__device__ __forceinline__ float b2f(ushort h) {
    union { float f; unsigned u; } u; u.u = ((unsigned)h) << 16; return u.f;
}
__device__ __forceinline__ float h2f(ushort u) {
    _Float16 h; __builtin_memcpy(&h, &u, 2); return (float)h;
}
__device__ __forceinline__ ushort f2h(float f) {
    _Float16 h = (_Float16)f; ushort u; __builtin_memcpy(&u, &h, 2); return u;
}
__device__ __forceinline__ int load_idx(const int* __restrict__ idx, size_t pos,
                                        int mode, int n) {
    int v = mode ? idx[2 * pos] : idx[pos];
    return v < 0 ? 0 : (v >= n ? n - 1 : v);
}
__device__ __forceinline__ float load_f(const void* p, size_t i, int bf) {
    return bf ? b2f(((const ushort*)p)[i]) : ((const float*)p)[i];
}

// NAMED union type; declared with leading __shared__ (R13-proven syntax).
// (R14 bug: `union {...} __shared__ sm;` applied the attribute to the TYPE,
//  making sm a per-thread stack variable -> garbage cross-thread reads.)
union K1Smem {
    struct { float sW[3][DIM * DIM]; float sx[8][DIM]; } qkv;   // 13.3 KB
    struct { int h[NCMAX]; } place;                             //  1 KB
};

// ---------------------------------------------------------------------------
// K1: blocks [0,PBLK) = place (deterministic sub-slot scatter, block-private
// LDS cursors, sentinel padding); blocks [PBLK,..) = QKV GEMM (f16 out,
// Q pre-scaled 1/sqrt(32), KV interleaved 128 B/node). Independent phases.
// ---------------------------------------------------------------------------
__global__ void __launch_bounds__(256)
qkv_place_kernel(const void* __restrict__ x_, const int* __restrict__ idx,
                 const void* __restrict__ Wq_, const void* __restrict__ Wk_,
                 const void* __restrict__ Wv_, int N, int E, int nc,
                 ushort* __restrict__ Q, ushort* __restrict__ KV,
                 unsigned* __restrict__ bedges) {
    __shared__ K1Smem sm;
    __shared__ int sBf, sMode;

    const int tid = threadIdx.x;
    if (tid < 64) {
        int e = (((const ushort*)x_)[2 * tid] >> 7) & 0xFF;
        unsigned long long bb = __ballot(e >= 100 && e <= 135);
        unsigned long long mm = __ballot(idx[2 * tid + 1] != 0);
        if (tid == 0) { sBf = (__popcll(bb) >= 56); sMode = (mm == 0ULL); }
    }
    __syncthreads();
    const int bf = sBf, mode = sMode;

    if (blockIdx.x < PBLK) {
        // ---- place ----
        const int pb = blockIdx.x;
        for (int i = tid; i < nc; i += 256) sm.place.h[i] = 0;
        __syncthreads();
        const int per = (E + PBLK - 1) / PBLK;
        const int e0 = pb * per;
        const int e1 = min(e0 + per, E);
        for (int e = e0 + tid; e < e1; e += 256) {
            const int r = load_idx(idx, (size_t)E + e, mode, N);
            const int s = load_idx(idx, (size_t)e, mode, N);
            const int cb = r >> 9;
            const int p = atomicAdd(&sm.place.h[cb], 1);
            if (p < SUBCAP)
                bedges[(size_t)cb * REGSZ + pb * SUBCAP + p] =
                    (unsigned)s | ((unsigned)(r & (RCR - 1)) << 17);
        }
        __syncthreads();
        // sentinel-pad unused slots of this block's cells
        for (int i = tid; i < nc * SUBCAP; i += 256) {
            const int c = i / SUBCAP;
            const int q = i - c * SUBCAP;
            if (q >= sm.place.h[c])
                bedges[(size_t)c * REGSZ + pb * SUBCAP + q] = SENT;
        }
        return;
    }

    // ---- QKV GEMM ----
    for (int i = tid; i < DIM * DIM; i += 256) {
        sm.qkv.sW[0][i] = load_f(Wq_, i, bf);
        sm.qkv.sW[1][i] = load_f(Wk_, i, bf);
        sm.qkv.sW[2][i] = load_f(Wv_, i, bf);
    }
    const int lr  = tid >> 5;
    const int d   = tid & 31;
    const int row = (blockIdx.x - PBLK) * 8 + lr;
    if (row < N) sm.qkv.sx[lr][d] = load_f(x_, (size_t)row * DIM + d, bf);
    __syncthreads();
    if (row >= N) return;

    float aq = 0.f, ak = 0.f, av = 0.f;
#pragma unroll
    for (int k = 0; k < DIM; ++k) {
        const float xk = sm.qkv.sx[lr][k];
        aq += xk * sm.qkv.sW[0][k * DIM + d];
        ak += xk * sm.qkv.sW[1][k * DIM + d];
        av += xk * sm.qkv.sW[2][k * DIM + d];
    }
    Q[(size_t)row * DIM + d]      = f2h(aq * 0.17677669529663687f);
    KV[(size_t)row * 64 + d]      = f2h(ak);
    KV[(size_t)row * 64 + 32 + d] = f2h(av);
}

// ---------------------------------------------------------------------------
// K2 (sortagg): one block per 128-receiver quarter-region (784 blocks).
// Scan region slot area (L2-hot, shared x4), filter own quarter, LDS
// counting-sort, then x2-pipelined wave-per-receiver agg with senders from
// LDS. Fused normalize + @Wo + residual epilogue.
// ---------------------------------------------------------------------------
__global__ void __launch_bounds__(256)
sortagg_kernel(const ushort* __restrict__ Q, const ushort* __restrict__ KV,
               const unsigned* __restrict__ bedges, const void* __restrict__ x_,
               const void* __restrict__ Wo_, int N, float* __restrict__ out) {
    __shared__ unsigned eS[QCAP];          // 9.7 KB  (sender ids, sorted)
    __shared__ int h[128], off[128], cur[128];
    __shared__ int wsum[2];
    __shared__ unsigned sQ[128 * 16];      // 8 KB
    __shared__ float accS[128][DIM + 1];   // 16.9 KB
    __shared__ float Zs[128];
    __shared__ float sWo[DIM * DIM];       // 4 KB
    __shared__ int sBf;

    const int tid = threadIdx.x;
    if (tid < 64) {
        int e = (((const ushort*)x_)[2 * tid] >> 7) & 0xFF;
        unsigned long long bb = __ballot(e >= 100 && e <= 135);
        if (tid == 0) sBf = (__popcll(bb) >= 56);
    }
    const int c  = blockIdx.x >> 2;        // region
    const int qd = blockIdx.x & 3;         // quarter
    const int r0 = c * RCR + qd * 128;
    const int nr = min(128, N - r0);
    if (tid < 128) h[tid] = 0;
    __syncthreads();
    const int bf = sBf;
    if (nr <= 0) return;

    for (int i = tid; i < DIM * DIM; i += 256) sWo[i] = load_f(Wo_, i, bf);
    for (int i = tid; i < nr * 16; i += 256)
        sQ[i] = ((const unsigned*)(Q + (size_t)r0 * DIM))[i];

    const unsigned* reg = bedges + (size_t)c * REGSZ;
    // pass 1: count this quarter's receivers
    for (int i = tid; i < REGSZ; i += 256) {
        const unsigned e = reg[i];
        if (e != SENT && (int)((e >> 24) & 3) == qd)
            atomicAdd(&h[(e >> 17) & 127], 1);
    }
    __syncthreads();
    // exclusive scan of 128 counts (2 waves)
    {
        const int lane = tid & 63, w2 = tid >> 6;
        const int v = (tid < 128) ? h[tid] : 0;
        int x = v;
#pragma unroll
        for (int o = 1; o < 64; o <<= 1) {
            int t = __shfl_up(x, o); if (lane >= o) x += t;
        }
        if (tid < 128 && lane == 63) wsum[w2] = x;
        __syncthreads();
        if (tid < 128) {
            const int base = (w2 == 1) ? wsum[0] : 0;
            off[tid] = base + x - v;
            cur[tid] = off[tid];
        }
    }
    __syncthreads();
    // pass 2: place senders sorted by receiver
    for (int i = tid; i < REGSZ; i += 256) {
        const unsigned e = reg[i];
        if (e != SENT && (int)((e >> 24) & 3) == qd) {
            const int p = atomicAdd(&cur[(e >> 17) & 127], 1);
            if (p < QCAP) eS[p] = e & 0x1FFFF;
        }
    }
    __syncthreads();

    // ---- aggregation: wave-per-receiver, x2 software pipeline ----
    const int w    = tid >> 6;
    const int lane = tid & 63;
    const int i8   = lane >> 3;   // edge sub-slot 0..7
    const int j    = lane & 7;    // channel group 0..7

    for (int rl = w; rl < nr; rl += 4) {
        const int deg = h[rl];
        const int o0  = off[rl];
        const ushort4 qh = *(const ushort4*)((const ushort*)sQ + rl * DIM + j * 4);
        const float q0 = h2f(qh.x), q1 = h2f(qh.y), q2 = h2f(qh.z), q3 = h2f(qh.w);

        float ax = 0.f, ay = 0.f, az = 0.f, aw = 0.f, zs = 0.f;
        const int chunks = (deg + 7) >> 3;
        const int dm1 = deg - 1;

        int cc = 0;
        for (; cc + 2 <= chunks; cc += 2) {
            const int c0 = cc * 8 + i8;
            const int c1 = c0 + 8;
            const bool ok0 = (c0 < deg);
            const bool ok1 = (c1 < deg);
            const int sA = (int)eS[o0 + (ok0 ? c0 : dm1)];
            const int sB = (int)eS[o0 + (ok1 ? c1 : dm1)];
            const ushort* kvA = KV + (size_t)sA * 64;
            const ushort* kvB = KV + (size_t)sB * 64;

            const ushort4 khA = *(const ushort4*)(kvA + j * 4);
            const ushort4 vhA = *(const ushort4*)(kvA + 32 + j * 4);
            const ushort4 khB = *(const ushort4*)(kvB + j * 4);
            const ushort4 vhB = *(const ushort4*)(kvB + 32 + j * 4);

            float pA = h2f(khA.x) * q0;
            float pB = h2f(khB.x) * q0;
            pA = fmaf(h2f(khA.y), q1, pA);  pB = fmaf(h2f(khB.y), q1, pB);
            pA = fmaf(h2f(khA.z), q2, pA);  pB = fmaf(h2f(khB.z), q2, pB);
            pA = fmaf(h2f(khA.w), q3, pA);  pB = fmaf(h2f(khB.w), q3, pB);

            pA += __shfl_xor(pA, 1);        pB += __shfl_xor(pB, 1);
            pA += __shfl_xor(pA, 2);        pB += __shfl_xor(pB, 2);
            pA += __shfl_xor(pA, 4);        pB += __shfl_xor(pB, 4);

            pA = fminf(fmaxf(pA, -60.f), 60.f);
            pB = fminf(fmaxf(pB, -60.f), 60.f);
            const float aA = ok0 ? __expf(pA) : 0.f;
            const float aB = ok1 ? __expf(pB) : 0.f;

            ax = fmaf(h2f(vhA.x), aA, ax);  ax = fmaf(h2f(vhB.x), aB, ax);
            ay = fmaf(h2f(vhA.y), aA, ay);  ay = fmaf(h2f(vhB.y), aB, ay);
            az = fmaf(h2f(vhA.z), aA, az);  az = fmaf(h2f(vhB.z), aB, az);
            aw = fmaf(h2f(vhA.w), aA, aw);  aw = fmaf(h2f(vhB.w), aB, aw);
            zs += aA + aB;
        }
        if (cc < chunks) {                   // odd remainder chunk
            const int cx = cc * 8 + i8;
            const bool ok = (cx < deg);
            const int s = (int)eS[o0 + (ok ? cx : dm1)];
            const ushort* kv = KV + (size_t)s * 64;
            const ushort4 kh = *(const ushort4*)(kv + j * 4);
            const ushort4 vh = *(const ushort4*)(kv + 32 + j * 4);

            float p = h2f(kh.x) * q0;
            p = fmaf(h2f(kh.y), q1, p);
            p = fmaf(h2f(kh.z), q2, p);
            p = fmaf(h2f(kh.w), q3, p);
            p += __shfl_xor(p, 1);
            p += __shfl_xor(p, 2);
            p += __shfl_xor(p, 4);
            p = fminf(fmaxf(p, -60.f), 60.f);
            const float a = ok ? __expf(p) : 0.f;

            ax = fmaf(h2f(vh.x), a, ax);
            ay = fmaf(h2f(vh.y), a, ay);
            az = fmaf(h2f(vh.z), a, az);
            aw = fmaf(h2f(vh.w), a, aw);
            zs += a;
        }
#pragma unroll
        for (int o = 8; o < 64; o <<= 1) {
            ax += __shfl_xor(ax, o); ay += __shfl_xor(ay, o);
            az += __shfl_xor(az, o); aw += __shfl_xor(aw, o);
            zs += __shfl_xor(zs, o);
        }
        if (i8 == 0) {
            float* ar = accS[rl];
            ar[j * 4 + 0] = ax; ar[j * 4 + 1] = ay;
            ar[j * 4 + 2] = az; ar[j * 4 + 3] = aw;
            if (j == 0) Zs[rl] = zs;
        }
    }
    __syncthreads();

    // epilogue: 256 threads = 8 rows x 32 cols, 16 iters covers 128 rows
    const int lr = tid >> 5;
    const int d  = tid & 31;
#pragma unroll 4
    for (int it = 0; it < 16; ++it) {
        const int rl = it * 8 + lr;
        if (rl < nr) {
            const float inv = 1.f / (Zs[rl] + 1e-6f);
            float o = 0.f;
#pragma unroll
            for (int k = 0; k < DIM; ++k) o += accS[rl][k] * sWo[k * DIM + d];
            const size_t oi = (size_t)(r0 + rl) * DIM + d;
            out[oi] = load_f(x_, oi, bf) + inv * o;
        }
    }
}

// ---------------------------------------------------------------------------
extern "C" void kernel_launch(void* const* d_in, const int* in_sizes, int n_in,
                              void* d_out, int out_size, void* d_ws, size_t ws_size,
                              hipStream_t stream) {
    const void* x   = d_in[0];
    const int*  idx = (const int*)d_in[1];
    const void* Wq  = d_in[2];
    const void* Wk  = d_in[3];
    const void* Wv  = d_in[4];
    const void* Wo  = d_in[5];
    float* out = (float*)d_out;           // fp32 reference output

    const int N = in_sizes[0] / DIM;      // 100000
    const int E = in_sizes[1] / 2;        // 1600000
    const int nc = (N + RCR - 1) / RCR;   // 196 regions
    const size_t N32 = (size_t)N * DIM;

    // Workspace (~29.3 MB): Q f16 | KV f16 | bedges (nc*REGSZ)
    ushort*   Q      = (ushort*)d_ws;
    ushort*   KV     = Q + N32;                          // N * 64 halves
    unsigned* bedges = (unsigned*)(KV + (size_t)N * 64); // nc * REGSZ ints

    const int qkv_blocks = (N + 7) / 8;
    qkv_place_kernel<<<PBLK + qkv_blocks, 256, 0, stream>>>(
        x, idx, Wq, Wk, Wv, N, E, nc, Q, KV, bedges);

    sortagg_kernel<<<nc * 4, 256, 0, stream>>>(Q, KV, bedges, x, Wo, N, out);
}

// Round 16
// 193.626 us; speedup vs baseline: 1.7306x; 1.6046x over previous
//
#include <hip/hip_runtime.h>
#include <hip/hip_bf16.h>

#define DIM 32
#define RCR 512             // receivers per region (r_local = 9 bits)
#define NCMAX 256           // max regions (N <= 131072)
#define PBLK 256            // place blocks
#define SUBCAP 80           // ints per (region, place-block) cell; mean 32, +8.7 sigma
#define REGSZ (PBLK * SUBCAP)   // 20480 ints per region
#define CAPC 9216           // rsort LDS stage cap; region mean 8163, +11 sigma

// ---------------- f16 / bf16 <-> fp32 helpers ------------------------------
__device__ __forceinline__ float b2f(ushort h) {
    union { float f; unsigned u; } u; u.u = ((unsigned)h) << 16; return u.f;
}
__device__ __forceinline__ float h2f(ushort u) {
    _Float16 h; __builtin_memcpy(&h, &u, 2); return (float)h;
}
__device__ __forceinline__ ushort f2h(float f) {
    _Float16 h = (_Float16)f; ushort u; __builtin_memcpy(&u, &h, 2); return u;
}
__device__ __forceinline__ int load_idx(const int* __restrict__ idx, size_t pos,
                                        int mode, int n) {
    int v = mode ? idx[2 * pos] : idx[pos];
    return v < 0 ? 0 : (v >= n ? n - 1 : v);
}
__device__ __forceinline__ float load_f(const void* p, size_t i, int bf) {
    return bf ? b2f(((const ushort*)p)[i]) : ((const float*)p)[i];
}

// Named union type, leading __shared__ on the variable (R13-proven syntax).
union K1Smem {
    struct { float sW[3][DIM * DIM]; float sx[8][DIM]; } qkv;   // 13.3 KB
    struct { int h[NCMAX]; } place;                             //  1 KB
};

// ---------------------------------------------------------------------------
// K1: blocks [0,PBLK) = deterministic place (block-private LDS cursors into
// fixed cells, fill counts -> hcnt, NO sentinels / NO global atomics);
// blocks [PBLK,..) = QKV GEMM (f16, Q pre-scaled 1/sqrt(32), KV interleaved
// 128 B/node). Phases are data-independent.
// ---------------------------------------------------------------------------
__global__ void __launch_bounds__(256)
qkv_place_kernel(const void* __restrict__ x_, const int* __restrict__ idx,
                 const void* __restrict__ Wq_, const void* __restrict__ Wk_,
                 const void* __restrict__ Wv_, int N, int E, int nc,
                 ushort* __restrict__ Q, ushort* __restrict__ KV,
                 unsigned* __restrict__ bedges, int* __restrict__ hcnt) {
    __shared__ K1Smem sm;
    __shared__ int sBf, sMode;

    const int tid = threadIdx.x;
    if (tid < 64) {
        int e = (((const ushort*)x_)[2 * tid] >> 7) & 0xFF;
        unsigned long long bb = __ballot(e >= 100 && e <= 135);
        unsigned long long mm = __ballot(idx[2 * tid + 1] != 0);
        if (tid == 0) { sBf = (__popcll(bb) >= 56); sMode = (mm == 0ULL); }
    }
    __syncthreads();
    const int bf = sBf, mode = sMode;

    if (blockIdx.x < PBLK) {
        // ---- place ----
        const int pb = blockIdx.x;
        for (int i = tid; i < nc; i += 256) sm.place.h[i] = 0;
        __syncthreads();
        const int per = (E + PBLK - 1) / PBLK;
        const int e0 = pb * per;
        const int e1 = min(e0 + per, E);
        for (int e = e0 + tid; e < e1; e += 256) {
            const int r = load_idx(idx, (size_t)E + e, mode, N);
            const int s = load_idx(idx, (size_t)e, mode, N);
            const int cb = r >> 9;
            const int p = atomicAdd(&sm.place.h[cb], 1);
            if (p < SUBCAP)
                bedges[(size_t)cb * REGSZ + pb * SUBCAP + p] =
                    (unsigned)s | ((unsigned)(r & (RCR - 1)) << 17);
        }
        __syncthreads();
        for (int i = tid; i < nc; i += 256)
            hcnt[i * PBLK + pb] = min(sm.place.h[i], SUBCAP);
        return;
    }

    // ---- QKV GEMM ----
    for (int i = tid; i < DIM * DIM; i += 256) {
        sm.qkv.sW[0][i] = load_f(Wq_, i, bf);
        sm.qkv.sW[1][i] = load_f(Wk_, i, bf);
        sm.qkv.sW[2][i] = load_f(Wv_, i, bf);
    }
    const int lr  = tid >> 5;
    const int d   = tid & 31;
    const int row = (blockIdx.x - PBLK) * 8 + lr;
    if (row < N) sm.qkv.sx[lr][d] = load_f(x_, (size_t)row * DIM + d, bf);
    __syncthreads();
    if (row >= N) return;

    float aq = 0.f, ak = 0.f, av = 0.f;
#pragma unroll
    for (int k = 0; k < DIM; ++k) {
        const float xk = sm.qkv.sx[lr][k];
        aq += xk * sm.qkv.sW[0][k * DIM + d];
        ak += xk * sm.qkv.sW[1][k * DIM + d];
        av += xk * sm.qkv.sW[2][k * DIM + d];
    }
    Q[(size_t)row * DIM + d]      = f2h(aq * 0.17677669529663687f);
    KV[(size_t)row * 64 + d]      = f2h(ak);
    KV[(size_t)row * 64 + 32 + d] = f2h(av);
}

// ---------------------------------------------------------------------------
// K2 (rsort): one 1024-thread block per region. Stage real edges (cell-
// bounded via hcnt) compactly into LDS, counting-sort by r_local, write back
// in place (sender only) + per-receiver rbase/rcount CSR.
// ---------------------------------------------------------------------------
__global__ void __launch_bounds__(1024)
rsort_kernel(unsigned* __restrict__ bedges, const int* __restrict__ hcnt,
             int* __restrict__ rbase, int* __restrict__ rcount, int N) {
    __shared__ unsigned eL[CAPC];     // 36.9 KB
    __shared__ int cnt[RCR];
    __shared__ int fills[PBLK];
    __shared__ int wsum[8];
    __shared__ int nEdges;

    const int tid = threadIdx.x;
    const int c = blockIdx.x;
    const size_t s0 = (size_t)c * REGSZ;

    if (tid < RCR) cnt[tid] = 0;
    if (tid == 0) nEdges = 0;
    for (int i = tid; i < PBLK; i += 1024) fills[i] = hcnt[c * PBLK + i];
    __syncthreads();

    // stage real edges compactly + count receivers
    for (int i = tid; i < REGSZ; i += 1024) {
        const int cell = i / SUBCAP;
        const int q    = i - cell * SUBCAP;
        if (q < fills[cell]) {
            const unsigned e = bedges[s0 + i];
            const int p = atomicAdd(&nEdges, 1);
            if (p < CAPC) {
                eL[p] = e;
                atomicAdd(&cnt[(e >> 17) & (RCR - 1)], 1);
            }
        }
    }
    __syncthreads();

    // exclusive scan of cnt[512] (8 waves)
    const int lane = tid & 63, w = tid >> 6;
    const int v = (tid < RCR) ? cnt[tid] : 0;
    int x = v;
#pragma unroll
    for (int o = 1; o < 64; o <<= 1) {
        int t = __shfl_up(x, o); if (lane >= o) x += t;
    }
    if (tid < RCR && lane == 63) wsum[w] = x;
    __syncthreads();
    if (tid == 0) {
        int a = 0;
#pragma unroll
        for (int k = 0; k < 8; ++k) { int t = wsum[k]; wsum[k] = a; a += t; }
    }
    __syncthreads();
    int excl = 0;
    if (tid < RCR) {
        excl = x - v + wsum[w];
        rbase[c * RCR + tid]  = (int)s0 + excl;
        rcount[c * RCR + tid] = v;
    }
    __syncthreads();
    if (tid < RCR) cnt[tid] = (int)s0 + excl;   // reuse as global cursor
    __syncthreads();

    const int m = min(nEdges, CAPC);
    for (int i = tid; i < m; i += 1024) {
        const unsigned e = eL[i];
        const int p = atomicAdd(&cnt[(e >> 17) & (RCR - 1)], 1);
        bedges[p] = e & 0x1FFFF;
    }
}

// ---------------------------------------------------------------------------
// K3 (agg): R12's proven kernel, byte-identical. Wave-per-receiver over CSR,
// x2 software-pipelined chunk loop, fused normalize + @Wo + residual.
// ---------------------------------------------------------------------------
__global__ void __launch_bounds__(256)
agg_kernel(const ushort* __restrict__ Q, const ushort* __restrict__ KV,
           const unsigned* __restrict__ bedges, const int* __restrict__ rbase,
           const int* __restrict__ rcount, const void* __restrict__ x_,
           const void* __restrict__ Wo_, int N, float* __restrict__ out) {
    __shared__ float sWo[DIM * DIM];
    __shared__ float accS[32][DIM + 1];
    __shared__ float Zs[32];
    __shared__ unsigned sQ[32 * 16];
    __shared__ int sBf;

    const int tid = threadIdx.x;
    if (tid < 64) {
        int e = (((const ushort*)x_)[2 * tid] >> 7) & 0xFF;
        unsigned long long bb = __ballot(e >= 100 && e <= 135);
        if (tid == 0) sBf = (__popcll(bb) >= 56);
    }
    const int r0 = blockIdx.x * 32;
    const int nr = min(32, N - r0);
    __syncthreads();
    const int bf = sBf;

    for (int i = tid; i < DIM * DIM; i += 256) sWo[i] = load_f(Wo_, i, bf);
    for (int i = tid; i < nr * 16; i += 256)
        sQ[i] = ((const unsigned*)(Q + (size_t)r0 * DIM))[i];
    __syncthreads();

    const int w    = tid >> 6;
    const int lane = tid & 63;
    const int i8   = lane >> 3;   // edge sub-slot 0..7
    const int j    = lane & 7;    // channel group 0..7

    for (int rl = w; rl < nr; rl += 4) {
        const int r   = r0 + rl;
        const int deg = rcount[r];
        const int o0  = rbase[r];
        const ushort4 qh = *(const ushort4*)((const ushort*)sQ + rl * DIM + j * 4);
        const float q0 = h2f(qh.x), q1 = h2f(qh.y), q2 = h2f(qh.z), q3 = h2f(qh.w);

        float ax = 0.f, ay = 0.f, az = 0.f, aw = 0.f, zs = 0.f;
        const int chunks = (deg + 7) >> 3;
        const int dm1 = deg - 1;

        int cc = 0;
        for (; cc + 2 <= chunks; cc += 2) {
            const int c0 = cc * 8 + i8;
            const int c1 = c0 + 8;
            const bool ok0 = (c0 < deg);
            const bool ok1 = (c1 < deg);
            const int sA = (int)bedges[o0 + (ok0 ? c0 : dm1)];
            const int sB = (int)bedges[o0 + (ok1 ? c1 : dm1)];
            const ushort* kvA = KV + (size_t)sA * 64;
            const ushort* kvB = KV + (size_t)sB * 64;

            const ushort4 khA = *(const ushort4*)(kvA + j * 4);
            const ushort4 vhA = *(const ushort4*)(kvA + 32 + j * 4);
            const ushort4 khB = *(const ushort4*)(kvB + j * 4);
            const ushort4 vhB = *(const ushort4*)(kvB + 32 + j * 4);

            float pA = h2f(khA.x) * q0;
            float pB = h2f(khB.x) * q0;
            pA = fmaf(h2f(khA.y), q1, pA);  pB = fmaf(h2f(khB.y), q1, pB);
            pA = fmaf(h2f(khA.z), q2, pA);  pB = fmaf(h2f(khB.z), q2, pB);
            pA = fmaf(h2f(khA.w), q3, pA);  pB = fmaf(h2f(khB.w), q3, pB);

            pA += __shfl_xor(pA, 1);        pB += __shfl_xor(pB, 1);
            pA += __shfl_xor(pA, 2);        pB += __shfl_xor(pB, 2);
            pA += __shfl_xor(pA, 4);        pB += __shfl_xor(pB, 4);

            pA = fminf(fmaxf(pA, -60.f), 60.f);
            pB = fminf(fmaxf(pB, -60.f), 60.f);
            const float aA = ok0 ? __expf(pA) : 0.f;
            const float aB = ok1 ? __expf(pB) : 0.f;

            ax = fmaf(h2f(vhA.x), aA, ax);  ax = fmaf(h2f(vhB.x), aB, ax);
            ay = fmaf(h2f(vhA.y), aA, ay);  ay = fmaf(h2f(vhB.y), aB, ay);
            az = fmaf(h2f(vhA.z), aA, az);  az = fmaf(h2f(vhB.z), aB, az);
            aw = fmaf(h2f(vhA.w), aA, aw);  aw = fmaf(h2f(vhB.w), aB, aw);
            zs += aA + aB;
        }
        if (cc < chunks) {                   // odd remainder chunk
            const int cx = cc * 8 + i8;
            const bool ok = (cx < deg);
            const int s = (int)bedges[o0 + (ok ? cx : dm1)];
            const ushort* kv = KV + (size_t)s * 64;
            const ushort4 kh = *(const ushort4*)(kv + j * 4);
            const ushort4 vh = *(const ushort4*)(kv + 32 + j * 4);

            float p = h2f(kh.x) * q0;
            p = fmaf(h2f(kh.y), q1, p);
            p = fmaf(h2f(kh.z), q2, p);
            p = fmaf(h2f(kh.w), q3, p);
            p += __shfl_xor(p, 1);
            p += __shfl_xor(p, 2);
            p += __shfl_xor(p, 4);
            p = fminf(fmaxf(p, -60.f), 60.f);
            const float a = ok ? __expf(p) : 0.f;

            ax = fmaf(h2f(vh.x), a, ax);
            ay = fmaf(h2f(vh.y), a, ay);
            az = fmaf(h2f(vh.z), a, az);
            aw = fmaf(h2f(vh.w), a, aw);
            zs += a;
        }
#pragma unroll
        for (int o = 8; o < 64; o <<= 1) {
            ax += __shfl_xor(ax, o); ay += __shfl_xor(ay, o);
            az += __shfl_xor(az, o); aw += __shfl_xor(aw, o);
            zs += __shfl_xor(zs, o);
        }
        if (i8 == 0) {
            float* ar = accS[rl];
            ar[j * 4 + 0] = ax; ar[j * 4 + 1] = ay;
            ar[j * 4 + 2] = az; ar[j * 4 + 3] = aw;
            if (j == 0) Zs[rl] = zs;
        }
    }
    __syncthreads();

    const int lr = tid >> 5;
    const int d  = tid & 31;
#pragma unroll
    for (int it = 0; it < 4; ++it) {
        const int rl = it * 8 + lr;
        if (rl < nr) {
            const float inv = 1.f / (Zs[rl] + 1e-6f);
            float o = 0.f;
#pragma unroll
            for (int k = 0; k < DIM; ++k) o += accS[rl][k] * sWo[k * DIM + d];
            const size_t oi = (size_t)(r0 + rl) * DIM + d;
            out[oi] = load_f(x_, oi, bf) + inv * o;
        }
    }
}

// ---------------------------------------------------------------------------
extern "C" void kernel_launch(void* const* d_in, const int* in_sizes, int n_in,
                              void* d_out, int out_size, void* d_ws, size_t ws_size,
                              hipStream_t stream) {
    const void* x   = d_in[0];
    const int*  idx = (const int*)d_in[1];
    const void* Wq  = d_in[2];
    const void* Wk  = d_in[3];
    const void* Wv  = d_in[4];
    const void* Wo  = d_in[5];
    float* out = (float*)d_out;           // fp32 reference output

    const int N = in_sizes[0] / DIM;      // 100000
    const int E = in_sizes[1] / 2;        // 1600000
    const int nc = (N + RCR - 1) / RCR;   // 196 regions
    const size_t N32 = (size_t)N * DIM;

    // Workspace (~36.3 MB): Q f16 | KV f16 | bedges | hcnt | rbase | rcount
    ushort*   Q      = (ushort*)d_ws;
    ushort*   KV     = Q + N32;                          // N * 64 halves
    unsigned* bedges = (unsigned*)(KV + (size_t)N * 64); // nc * REGSZ
    int*      hcnt   = (int*)(bedges + (size_t)nc * REGSZ); // nc * PBLK
    int*      rbase  = hcnt + (size_t)nc * PBLK;
    int*      rcount = rbase + (size_t)nc * RCR;

    const int qkv_blocks = (N + 7) / 8;
    qkv_place_kernel<<<PBLK + qkv_blocks, 256, 0, stream>>>(
        x, idx, Wq, Wk, Wv, N, E, nc, Q, KV, bedges, hcnt);

    rsort_kernel<<<nc, 1024, 0, stream>>>(bedges, hcnt, rbase, rcount, N);

    agg_kernel<<<(N + 31) / 32, 256, 0, stream>>>(Q, KV, bedges, rbase,
                                                  rcount, x, Wo, N, out);
}